// Round 1
// baseline (919.322 us; speedup 1.0000x reference)
//
#include <hip/hip_runtime.h>
#include <hip/hip_bf16.h>

#define NN 20000
#define DD 512
#define EE 150000

typedef __attribute__((ext_vector_type(8))) short short8;
typedef __attribute__((ext_vector_type(4))) float floatx4;

static __device__ __forceinline__ float bfbits2f(unsigned short u) {
    unsigned int x = ((unsigned int)u) << 16;
    return __uint_as_float(x);
}

// ---------------- convert fp32 -> bf16 (vectorized) ----------------
__global__ __launch_bounds__(256) void k_convert_bf16(const float* __restrict__ in,
                                                      __hip_bfloat16* __restrict__ out, int n4) {
    int i = blockIdx.x * blockDim.x + threadIdx.x;
    if (i >= n4) return;
    float4 v = ((const float4*)in)[i];
    union { __hip_bfloat16 b[4]; ushort4 u; } cv;
    cv.b[0] = __float2bfloat16(v.x);
    cv.b[1] = __float2bfloat16(v.y);
    cv.b[2] = __float2bfloat16(v.z);
    cv.b[3] = __float2bfloat16(v.w);
    *(ushort4*)(out + 4l * i) = cv.u;
}

// ---------------- 512x512 transpose + convert to bf16 ----------------
// out[n*512+k] = in[k*512+n]
__global__ __launch_bounds__(1024) void k_transpose_bf16(const float* __restrict__ in,
                                                         __hip_bfloat16* __restrict__ out) {
    __shared__ float tile[32][33];
    int bx = blockIdx.x * 32;  // col (n) base
    int by = blockIdx.y * 32;  // row (k) base
    int tx = threadIdx.x, ty = threadIdx.y;
    tile[ty][tx] = in[(by + ty) * 512 + bx + tx];
    __syncthreads();
    out[(bx + ty) * 512 + by + tx] = __float2bfloat16(tile[tx][ty]);
}

// ---------------- bf16 MFMA GEMM: C[M,512] = A[M,512] @ B[512,512] ----------------
// A row-major bf16; Bt[n][k] = B[k][n] (bf16).  mode 0: store bf16 to Cb.
// mode 1: Cf = relu(C + addend). mode 2: Cf = C.
__global__ __launch_bounds__(256)
void k_gemm(const __hip_bfloat16* __restrict__ A, const __hip_bfloat16* __restrict__ Bt,
            float* __restrict__ Cf, __hip_bfloat16* __restrict__ Cb,
            const float* __restrict__ addend, int M, int mode) {
    __shared__ __hip_bfloat16 As[64][40];
    __shared__ __hip_bfloat16 Bs[64][40];
    const int tid = threadIdx.x;
    const int lane = tid & 63;
    const int wave = tid >> 6;
    const int row0 = blockIdx.x * 64;
    const int col0 = blockIdx.y * 64;
    const int wm = (wave >> 1) * 32;
    const int wn = (wave & 1) * 32;
    const int q = lane >> 4;
    const int l15 = lane & 15;

    const int sr = tid >> 2;         // staging row 0..63
    const int sc = (tid & 3) * 8;    // staging col {0,8,16,24}

    floatx4 acc[2][2];
#pragma unroll
    for (int a = 0; a < 2; a++)
#pragma unroll
        for (int b = 0; b < 2; b++) acc[a][b] = (floatx4){0.f, 0.f, 0.f, 0.f};

    const int arow = row0 + sr;
    const long aoff = (long)arow * 512;
    const long boff = (long)(col0 + sr) * 512;

    for (int k0 = 0; k0 < 512; k0 += 32) {
        uint4 av;
        if (arow < M) av = *(const uint4*)(A + aoff + k0 + sc);
        else av = (uint4){0u, 0u, 0u, 0u};
        uint4 bv = *(const uint4*)(Bt + boff + k0 + sc);
        __syncthreads();
        *(uint4*)(&As[sr][sc]) = av;
        *(uint4*)(&Bs[sr][sc]) = bv;
        __syncthreads();
        short8 afr[2], bfr[2];
#pragma unroll
        for (int mi = 0; mi < 2; mi++) afr[mi] = *(const short8*)(&As[wm + mi * 16 + l15][q * 8]);
#pragma unroll
        for (int ni = 0; ni < 2; ni++) bfr[ni] = *(const short8*)(&Bs[wn + ni * 16 + l15][q * 8]);
#pragma unroll
        for (int mi = 0; mi < 2; mi++)
#pragma unroll
            for (int ni = 0; ni < 2; ni++)
                acc[mi][ni] = __builtin_amdgcn_mfma_f32_16x16x32_bf16(afr[mi], bfr[ni], acc[mi][ni], 0, 0, 0);
    }

#pragma unroll
    for (int mi = 0; mi < 2; mi++)
#pragma unroll
        for (int ni = 0; ni < 2; ni++)
#pragma unroll
            for (int r = 0; r < 4; r++) {
                int grow = row0 + wm + mi * 16 + q * 4 + r;
                int gcol = col0 + wn + ni * 16 + l15;
                if (grow < M) {
                    float v = acc[mi][ni][r];
                    long idx = (long)grow * 512 + gcol;
                    if (mode == 0) Cb[idx] = __float2bfloat16(v);
                    else if (mode == 1) { v += addend[idx]; Cf[idx] = v > 0.f ? v : 0.f; }
                    else Cf[idx] = v;
                }
            }
}

// ---------------- el/er: per-row dot products ----------------
__global__ __launch_bounds__(256)
void k_el_er(const __hip_bfloat16* __restrict__ h, const float* __restrict__ al,
             const float* __restrict__ ar, float* __restrict__ el, float* __restrict__ er) {
    int wave = threadIdx.x >> 6, lane = threadIdx.x & 63;
    int row = blockIdx.x * 4 + wave;
    if (row >= NN) return;
    uint4 hv = *(const uint4*)(h + (long)row * 512 + lane * 8);
    const unsigned short* hs = (const unsigned short*)&hv;
    float4 a0 = *(const float4*)(al + lane * 8);
    float4 a1 = *(const float4*)(al + lane * 8 + 4);
    float4 r0 = *(const float4*)(ar + lane * 8);
    float4 r1 = *(const float4*)(ar + lane * 8 + 4);
    float sl = 0.f, sr = 0.f;
    float hf[8];
#pragma unroll
    for (int j = 0; j < 8; j++) hf[j] = bfbits2f(hs[j]);
    sl = hf[0] * a0.x + hf[1] * a0.y + hf[2] * a0.z + hf[3] * a0.w +
         hf[4] * a1.x + hf[5] * a1.y + hf[6] * a1.z + hf[7] * a1.w;
    sr = hf[0] * r0.x + hf[1] * r0.y + hf[2] * r0.z + hf[3] * r0.w +
         hf[4] * r1.x + hf[5] * r1.y + hf[6] * r1.z + hf[7] * r1.w;
#pragma unroll
    for (int off = 32; off > 0; off >>= 1) {
        sl += __shfl_down(sl, off);
        sr += __shfl_down(sr, off);
    }
    if (lane == 0) { el[row] = sl; er[row] = sr; }
}

// ---------------- CSR build ----------------
__global__ void k_zero_i32(int* p, int n) {
    int i = blockIdx.x * blockDim.x + threadIdx.x;
    if (i < n) p[i] = 0;
}

__global__ void k_count(const int* __restrict__ edges, int* __restrict__ deg) {
    int e = blockIdx.x * blockDim.x + threadIdx.x;
    if (e < EE) atomicAdd(&deg[edges[EE + e]], 1);
}

__global__ __launch_bounds__(1024)
void k_scan(const int* __restrict__ deg, int* __restrict__ row_ptr, int* __restrict__ cursor) {
    __shared__ int sm[1024];
    int t = threadIdx.x;
    const int CH = 20;
    int begin = t * CH;
    int end = begin + CH; if (end > NN) end = NN;
    int s = 0;
    if (begin < NN)
        for (int i = begin; i < end; i++) s += deg[i];
    sm[t] = s;
    __syncthreads();
    for (int off = 1; off < 1024; off <<= 1) {
        int v = (t >= off) ? sm[t - off] : 0;
        __syncthreads();
        sm[t] += v;
        __syncthreads();
    }
    int run = sm[t] - s;  // exclusive prefix
    if (begin < NN) {
        for (int i = begin; i < end; i++) {
            row_ptr[i] = run;
            cursor[i] = run;
            run += deg[i];
        }
        if (end == NN) row_ptr[NN] = run;
    }
}

__global__ void k_scatter(const int* __restrict__ edges, int* __restrict__ cursor,
                          int* __restrict__ csr_src) {
    int e = blockIdx.x * blockDim.x + threadIdx.x;
    if (e < EE) {
        int dst = edges[EE + e];
        int pos = atomicAdd(&cursor[dst], 1);
        csr_src[pos] = edges[e];
    }
}

// ---------------- per-dst edge softmax -> alpha ----------------
__global__ void k_alpha(const int* __restrict__ row_ptr, const int* __restrict__ csr_src,
                        const float* __restrict__ el, const float* __restrict__ er,
                        float* __restrict__ alpha) {
    int d = blockIdx.x * blockDim.x + threadIdx.x;
    if (d >= NN) return;
    int s0 = row_ptr[d], s1 = row_ptr[d + 1];
    if (s0 == s1) return;
    float erd = er[d];
    float m = -1e30f;
    for (int j = s0; j < s1; j++) {
        float v = el[csr_src[j]] + erd;
        v = v >= 0.f ? v : 0.2f * v;
        alpha[j] = v;
        m = fmaxf(m, v);
    }
    float denom = 0.f;
    for (int j = s0; j < s1; j++) {
        float w = expf(alpha[j] - m);
        alpha[j] = w;
        denom += w;
    }
    float inv = 1.f / denom;
    for (int j = s0; j < s1; j++) alpha[j] *= inv;
}

// ---------------- aggregate: t[dst] = sum alpha*h[src] (+prev)(+bias), write bf16 ----------------
__global__ __launch_bounds__(128)
void k_aggregate(const int* __restrict__ row_ptr, const int* __restrict__ csr_src,
                 const float* __restrict__ alpha, const __hip_bfloat16* __restrict__ h,
                 const float* __restrict__ out_prev, const float* __restrict__ bias,
                 __hip_bfloat16* __restrict__ t_out, int use_prev) {
    int d = blockIdx.x;
    int c = threadIdx.x * 4;
    int s0 = row_ptr[d], s1 = row_ptr[d + 1];
    float a0 = 0.f, a1 = 0.f, a2 = 0.f, a3 = 0.f;
    for (int j = s0; j < s1; j++) {
        int s = csr_src[j];
        float a = alpha[j];
        ushort4 raw = *(const ushort4*)(h + (long)s * 512 + c);
        a0 += a * bfbits2f(raw.x);
        a1 += a * bfbits2f(raw.y);
        a2 += a * bfbits2f(raw.z);
        a3 += a * bfbits2f(raw.w);
    }
    if (use_prev) {
        float4 pv = *(const float4*)(out_prev + (long)d * 512 + c);
        a0 += pv.x; a1 += pv.y; a2 += pv.z; a3 += pv.w;
    }
    float4 bv = *(const float4*)(bias + c);
    a0 += bv.x; a1 += bv.y; a2 += bv.z; a3 += bv.w;
    union { __hip_bfloat16 b[4]; ushort4 u; } cv;
    cv.b[0] = __float2bfloat16(a0);
    cv.b[1] = __float2bfloat16(a1);
    cv.b[2] = __float2bfloat16(a2);
    cv.b[3] = __float2bfloat16(a3);
    *(ushort4*)(t_out + (long)d * 512 + c) = cv.u;
}

extern "C" void kernel_launch(void* const* d_in, const int* in_sizes, int n_in,
                              void* d_out, int out_size, void* d_ws, size_t ws_size,
                              hipStream_t stream) {
    const float* x = (const float*)d_in[0];
    const int* edges[4] = {(const int*)d_in[1], (const int*)d_in[5], (const int*)d_in[9],
                           (const int*)d_in[13]};
    const float* W[4] = {(const float*)d_in[2], (const float*)d_in[6], (const float*)d_in[10],
                         (const float*)d_in[14]};
    const float* al[4] = {(const float*)d_in[3], (const float*)d_in[7], (const float*)d_in[11],
                          (const float*)d_in[15]};
    const float* ar[4] = {(const float*)d_in[4], (const float*)d_in[8], (const float*)d_in[12],
                          (const float*)d_in[16]};
    const float* Wl = (const float*)d_in[17];
    const float* bias = (const float*)d_in[18];
    float* out = (float*)d_out;

    char* w = (char*)d_ws;
    auto alloc = [&](size_t bytes) {
        char* p = w;
        w += (bytes + 255) & ~(size_t)255;
        return p;
    };
    __hip_bfloat16* x_bf = (__hip_bfloat16*)alloc((size_t)NN * DD * 2);
    __hip_bfloat16* h_bf = (__hip_bfloat16*)alloc((size_t)NN * DD * 2);
    __hip_bfloat16* t_bf = (__hip_bfloat16*)alloc((size_t)NN * DD * 2);
    float* xWl = (float*)alloc((size_t)NN * DD * 4);
    __hip_bfloat16* Wt[4];
    for (int i = 0; i < 4; i++) Wt[i] = (__hip_bfloat16*)alloc((size_t)DD * DD * 2);
    __hip_bfloat16* WlTt = (__hip_bfloat16*)alloc((size_t)DD * DD * 2);
    __hip_bfloat16* WlTb = (__hip_bfloat16*)alloc((size_t)DD * DD * 2);
    float* el = (float*)alloc((size_t)NN * 4);
    float* er = (float*)alloc((size_t)NN * 4);
    int* deg = (int*)alloc((size_t)NN * 4);
    int* row_ptr = (int*)alloc((size_t)(NN + 1) * 4);
    int* cursor = (int*)alloc((size_t)NN * 4);
    int* csr_src = (int*)alloc((size_t)EE * 4);
    float* alphaw = (float*)alloc((size_t)EE * 4);

    // one-time preprocessing
    k_convert_bf16<<<(NN * DD / 4 + 255) / 256, 256, 0, stream>>>(x, x_bf, NN * DD / 4);
    dim3 tb(32, 32), tg(16, 16);
    for (int i = 0; i < 4; i++) k_transpose_bf16<<<tg, tb, 0, stream>>>(W[i], Wt[i]);
    k_transpose_bf16<<<tg, tb, 0, stream>>>(Wl, WlTt);
    k_transpose_bf16<<<tg, tb, 0, stream>>>(Wl + 512 * 512, WlTb);

    dim3 gg((NN + 63) / 64, 8);
    // xWl = x @ Wl_top  (loop-invariant)
    k_gemm<<<gg, 256, 0, stream>>>(x_bf, WlTt, xWl, nullptr, nullptr, NN, 2);

    for (int i = 0; i < 4; i++) {
        // h = x @ W_i  (bf16 out)
        k_gemm<<<gg, 256, 0, stream>>>(x_bf, Wt[i], nullptr, h_bf, nullptr, NN, 0);
        k_el_er<<<NN / 4, 256, 0, stream>>>(h_bf, al[i], ar[i], el, er);
        // CSR build
        k_zero_i32<<<(NN + 255) / 256, 256, 0, stream>>>(deg, NN);
        k_count<<<(EE + 255) / 256, 256, 0, stream>>>(edges[i], deg);
        k_scan<<<1, 1024, 0, stream>>>(deg, row_ptr, cursor);
        k_scatter<<<(EE + 255) / 256, 256, 0, stream>>>(edges[i], cursor, csr_src);
        // edge softmax
        k_alpha<<<(NN + 255) / 256, 256, 0, stream>>>(row_ptr, csr_src, el, er, alphaw);
        // aggregate + prev + bias -> t (bf16)
        k_aggregate<<<NN, 128, 0, stream>>>(row_ptr, csr_src, alphaw, h_bf, out, bias, t_bf,
                                            i > 0 ? 1 : 0);
        // out = relu(xWl + t @ Wl_bot)
        k_gemm<<<gg, 256, 0, stream>>>(t_bf, WlTb, out, nullptr, xWl, NN, 1);
    }
}